// Round 2
// baseline (402.174 us; speedup 1.0000x reference)
//
#include <hip/hip_runtime.h>
#include <hip/hip_bf16.h>

#define NCELL 64
#define CIN 8
#define EE 4
#define DD 4
#define HH 256
#define WW 256

#define TW 32
#define TH 16
#define ZW (TW + 4)   // 36
#define ZH (TH + 4)   // 20
#define HW1 (TW + 2)  // 34
#define HH1 (TH + 2)  // 18
#define NCG 4         // cells per block in edge pass

#define COMP(v,i) ((i)==0?(v).x:(i)==1?(v).y:(i)==2?(v).z:(v).w)

__device__ __forceinline__ void fma4(float4& a, float s, float4 w) {
    a.x = fmaf(s, w.x, a.x);
    a.y = fmaf(s, w.y, a.y);
    a.z = fmaf(s, w.z, a.z);
    a.w = fmaf(s, w.w, a.w);
}

// float4 of 4 consecutive output-channel weights: {p[idx], p[s+idx], p[2s+idx], p[3s+idx]}
__device__ __forceinline__ float4 ld4s(const float* __restrict__ p, int stride, int idx) {
    return make_float4(p[idx], p[stride + idx], p[2 * stride + idx], p[3 * stride + idx]);
}

__device__ __forceinline__ float silu1(float v) { return v / (1.0f + __expf(-v)); }
__device__ __forceinline__ float4 silu4(float4 v) {
    return make_float4(silu1(v.x), silu1(v.y), silu1(v.z), silu1(v.w));
}

// 3x3 conv, 4 packed input channels (ibase..ibase+3), 4 packed output channels,
// computed for a vertical pair of pixels (ly0, ly0+1) at column lx.
// in: LDS plane of float4, row width LW. w: [o][i][3][3] with o-stride wstride.
template<int LW>
__device__ __forceinline__ void conv3x3_pair(const float4 (*in)[LW], int ly0, int lx,
                                             const float* __restrict__ w, int wstride,
                                             int ibase, float4& s0, float4& s1) {
#pragma unroll
    for (int dx = 0; dx < 3; ++dx) {
        const float4 a0 = in[ly0 + 0][lx + dx];
        const float4 a1 = in[ly0 + 1][lx + dx];
        const float4 a2 = in[ly0 + 2][lx + dx];
        const float4 a3 = in[ly0 + 3][lx + dx];
#pragma unroll
        for (int dy = 0; dy < 3; ++dy) {
            const float4 va = (dy == 0) ? a0 : (dy == 1) ? a1 : a2;
            const float4 vb = (dy == 0) ? a1 : (dy == 1) ? a2 : a3;
#pragma unroll
            for (int ci = 0; ci < 4; ++ci) {
                const float4 w4 = ld4s(w, wstride, (ibase + ci) * 9 + dy * 3 + dx);
                fma4(s0, COMP(va, ci), w4);
                fma4(s1, COMP(vb, ci), w4);
            }
        }
    }
}

__global__ __launch_bounds__(256) void zero_kernel(float* __restrict__ p) {
    // zero EE*HH*WW floats = 65536 float4
    int i = blockIdx.x * 256 + threadIdx.x;
    reinterpret_cast<float4*>(p)[i] = make_float4(0.f, 0.f, 0.f, 0.f);
}

__global__ __launch_bounds__(256) void edge_kernel(
    const float* __restrict__ x,
    const float* __restrict__ w_down, const float* __restrict__ b_down,
    const float* __restrict__ w_e1, const float* __restrict__ b_e1,
    const float* __restrict__ w_e2, const float* __restrict__ b_e2,
    float* __restrict__ A)   // pixel-major: A[(y*WW+x)*4 + e]
{
    __shared__ float4 zb[ZH][ZW];     // 11.25 KB
    __shared__ float4 h1b[HH1][HW1];  // 9.56 KB

    const int tid = threadIdx.x;
    const int ox = blockIdx.x * TW;
    const int oy = blockIdx.y * TH;
    const int n0 = blockIdx.z * NCG;

    const float4 be1 = make_float4(b_e1[0], b_e1[1], b_e1[2], b_e1[3]);
    const float4 be2 = make_float4(b_e2[0], b_e2[1], b_e2[2], b_e2[3]);
    const float4 bdn = make_float4(b_down[0], b_down[1], b_down[2], b_down[3]);

    float4 acc0 = make_float4(0.f, 0.f, 0.f, 0.f);
    float4 acc1 = make_float4(0.f, 0.f, 0.f, 0.f);

    for (int j = 0; j < NCG; ++j) {
        const int n = n0 + j;
        const float* __restrict__ xn = x + (size_t)n * CIN * HH * WW;

        // ---- z = 1x1 down conv over halo-2 region (packed float4 over E) ----
        for (int idx = tid; idx < ZH * ZW; idx += 256) {
            const int ly = idx / ZW, lx = idx - (idx / ZW) * ZW;
            const int gy = oy + ly - 2, gx = ox + lx - 2;
            float4 zv = make_float4(0.f, 0.f, 0.f, 0.f);
            if ((unsigned)gy < (unsigned)HH && (unsigned)gx < (unsigned)WW) {
                zv = bdn;
#pragma unroll
                for (int c = 0; c < CIN; ++c) {
                    const float xv = xn[(c * HH + gy) * WW + gx];
                    fma4(zv, xv, ld4s(w_down, CIN, c));
                }
            }
            zb[ly][lx] = zv;
        }
        __syncthreads();

        // ---- h1 = silu(3x3 conv e1) over halo-1 region: 9 row-pairs x 34 cols ----
        for (int t = tid; t < 9 * HW1; t += 256) {
            const int pr = t / HW1;
            const int lx = t - pr * HW1;
            const int ly0 = pr * 2;
            float4 s0 = be1, s1 = be1;
            conv3x3_pair<ZW>(zb, ly0, lx, w_e1, 36, 0, s0, s1);
            const int gx = ox + lx - 1;
            const int gy0 = oy + ly0 - 1;
            const bool xok = (unsigned)gx < (unsigned)WW;
            h1b[ly0 + 0][lx] = (xok && (unsigned)(gy0 + 0) < (unsigned)HH)
                                   ? silu4(s0) : make_float4(0.f, 0.f, 0.f, 0.f);
            h1b[ly0 + 1][lx] = (xok && (unsigned)(gy0 + 1) < (unsigned)HH)
                                   ? silu4(s1) : make_float4(0.f, 0.f, 0.f, 0.f);
        }
        __syncthreads();

        // ---- h2 = silu(3x3 conv e2) over 8 row-pairs x 32 cols, accumulate ----
        {
            const int py0 = (tid >> 5) * 2;
            const int px = tid & 31;
            float4 s0 = be2, s1 = be2;
            conv3x3_pair<HW1>(h1b, py0, px, w_e2, 36, 0, s0, s1);
            const float4 v0 = silu4(s0), v1 = silu4(s1);
            acc0.x += v0.x; acc0.y += v0.y; acc0.z += v0.z; acc0.w += v0.w;
            acc1.x += v1.x; acc1.y += v1.y; acc1.z += v1.z; acc1.w += v1.w;
        }
        __syncthreads();
    }

    // ---- atomic accumulate into A (pixel-major float4) ----
    const int py0 = (tid >> 5) * 2;
    const int px = tid & 31;
    const int gy0 = oy + py0, gx = ox + px;
    float* a0 = &A[((size_t)(gy0 + 0) * WW + gx) * 4];
    float* a1 = &A[((size_t)(gy0 + 1) * WW + gx) * 4];
    atomicAdd(a0 + 0, acc0.x); atomicAdd(a0 + 1, acc0.y);
    atomicAdd(a0 + 2, acc0.z); atomicAdd(a0 + 3, acc0.w);
    atomicAdd(a1 + 0, acc1.x); atomicAdd(a1 + 1, acc1.y);
    atomicAdd(a1 + 2, acc1.z); atomicAdd(a1 + 3, acc1.w);
}

__global__ __launch_bounds__(256) void node_kernel(
    const float* __restrict__ x, const float* __restrict__ A,
    const float* __restrict__ w_up, const float* __restrict__ b_up,
    const float* __restrict__ w_n1, const float* __restrict__ b_n1,
    const float* __restrict__ w_n2, const float* __restrict__ b_n2,
    const float* __restrict__ w_r, const float* __restrict__ b_r,
    float* __restrict__ out)
{
    __shared__ float4 xa[3][ZH][ZW];   // 33.75 KB: groups {x0-3, x4-7, Aup0-3}
    __shared__ float4 y1b[HH1][HW1];   // 9.56 KB

    const int tid = threadIdx.x;
    const int ox = blockIdx.x * TW;
    const int oy = blockIdx.y * TH;
    const int n = blockIdx.z;
    const float* __restrict__ xn = x + (size_t)n * CIN * HH * WW;

    const float4 bup = make_float4(b_up[0], b_up[1], b_up[2], b_up[3]);
    const float4 bn1 = make_float4(b_n1[0], b_n1[1], b_n1[2], b_n1[3]);
    const float4 bn2r = make_float4(b_n2[0] + b_r[0], b_n2[1] + b_r[1],
                                    b_n2[2] + b_r[2], b_n2[3] + b_r[3]);

    // ---- stage [x || up(A)] tile with halo 2, fusing the 1x1 up conv ----
    for (int idx = tid; idx < ZH * ZW; idx += 256) {
        const int ly = idx / ZW, lx = idx - (idx / ZW) * ZW;
        const int gy = oy + ly - 2, gx = ox + lx - 2;
        float4 g0 = make_float4(0.f, 0.f, 0.f, 0.f);
        float4 g1 = g0, au = g0;
        if ((unsigned)gy < (unsigned)HH && (unsigned)gx < (unsigned)WW) {
            g0 = make_float4(xn[(0 * HH + gy) * WW + gx], xn[(1 * HH + gy) * WW + gx],
                             xn[(2 * HH + gy) * WW + gx], xn[(3 * HH + gy) * WW + gx]);
            g1 = make_float4(xn[(4 * HH + gy) * WW + gx], xn[(5 * HH + gy) * WW + gx],
                             xn[(6 * HH + gy) * WW + gx], xn[(7 * HH + gy) * WW + gx]);
            const float4 a4 = reinterpret_cast<const float4*>(A)[gy * WW + gx];
            au = bup;
#pragma unroll
            for (int e = 0; e < 4; ++e) fma4(au, COMP(a4, e), ld4s(w_up, EE, e));
        }
        xa[0][ly][lx] = g0;
        xa[1][ly][lx] = g1;
        xa[2][ly][lx] = au;
    }
    __syncthreads();

    // ---- y1 = silu(3x3 conv n1, 12->4) over 9 row-pairs x 34 cols ----
    for (int t = tid; t < 9 * HW1; t += 256) {
        const int pr = t / HW1;
        const int lx = t - pr * HW1;
        const int ly0 = pr * 2;
        float4 s0 = bn1, s1 = bn1;
#pragma unroll
        for (int g = 0; g < 3; ++g)
            conv3x3_pair<ZW>(xa[g], ly0, lx, w_n1, 108, g * 4, s0, s1);
        const int gx = ox + lx - 1;
        const int gy0 = oy + ly0 - 1;
        const bool xok = (unsigned)gx < (unsigned)WW;
        y1b[ly0 + 0][lx] = (xok && (unsigned)(gy0 + 0) < (unsigned)HH)
                               ? silu4(s0) : make_float4(0.f, 0.f, 0.f, 0.f);
        y1b[ly0 + 1][lx] = (xok && (unsigned)(gy0 + 1) < (unsigned)HH)
                               ? silu4(s1) : make_float4(0.f, 0.f, 0.f, 0.f);
    }
    __syncthreads();

    // ---- out = 3x3 conv n2 (y1) + 1x1 conv r (x) over 8 row-pairs x 32 cols ----
    {
        const int py0 = (tid >> 5) * 2;
        const int px = tid & 31;
        float4 s0 = bn2r, s1 = bn2r;
        conv3x3_pair<HW1>(y1b, py0, px, w_n2, 36, 0, s0, s1);
        // residual 1x1 on x (groups 0,1 of xa), tile-center offset +2
#pragma unroll
        for (int g = 0; g < 2; ++g) {
            const float4 c0 = xa[g][py0 + 2][px + 2];
            const float4 c1 = xa[g][py0 + 3][px + 2];
#pragma unroll
            for (int ci = 0; ci < 4; ++ci) {
                const float4 w4 = ld4s(w_r, CIN, g * 4 + ci);
                fma4(s0, COMP(c0, ci), w4);
                fma4(s1, COMP(c1, ci), w4);
            }
        }
        const int gy0 = oy + py0, gx = ox + px;
#pragma unroll
        for (int o = 0; o < 4; ++o) {
            out[(((size_t)n * DD + o) * HH + gy0 + 0) * WW + gx] = COMP(s0, o);
            out[(((size_t)n * DD + o) * HH + gy0 + 1) * WW + gx] = COMP(s1, o);
        }
    }
}

extern "C" void kernel_launch(void* const* d_in, const int* in_sizes, int n_in,
                              void* d_out, int out_size, void* d_ws, size_t ws_size,
                              hipStream_t stream) {
    const float* x      = (const float*)d_in[0];
    const float* w_down = (const float*)d_in[1];
    const float* b_down = (const float*)d_in[2];
    const float* w_e1   = (const float*)d_in[3];
    const float* b_e1   = (const float*)d_in[4];
    const float* w_e2   = (const float*)d_in[5];
    const float* b_e2   = (const float*)d_in[6];
    const float* w_up   = (const float*)d_in[7];
    const float* b_up   = (const float*)d_in[8];
    const float* w_n1   = (const float*)d_in[9];
    const float* b_n1   = (const float*)d_in[10];
    const float* w_n2   = (const float*)d_in[11];
    const float* b_n2   = (const float*)d_in[12];
    const float* w_r    = (const float*)d_in[13];
    const float* b_r    = (const float*)d_in[14];
    float* out = (float*)d_out;

    float* A = (float*)d_ws;  // pixel-major (HH*WW, 4) floats = 1 MiB

    zero_kernel<<<dim3(256), dim3(256), 0, stream>>>(A);

    edge_kernel<<<dim3(WW / TW, HH / TH, NCELL / NCG), dim3(256), 0, stream>>>(
        x, w_down, b_down, w_e1, b_e1, w_e2, b_e2, A);

    node_kernel<<<dim3(WW / TW, HH / TH, NCELL), dim3(256), 0, stream>>>(
        x, A, w_up, b_up, w_n1, b_n1, w_n2, b_n2, w_r, b_r, out);
}